// Round 8
// baseline (1314.571 us; speedup 1.0000x reference)
//
#include <hip/hip_runtime.h>
#include <math.h>

// FrankWolfePolicyImprovement, fused: 4096 problems, one wave (64 lanes) each.
// Phases (single kernel, A resident in LDS throughout):
//   1. anchor QP  (Schur-reduced d=68 ADMM, 80 it, Sinv rows in VGPRs)
//   2. tanh MLP gradient
//   3. LMO QP on row-normalized A (normalization folded into registers)
//   4. blend + store
//
// Round-8: single change vs R6 (best known, 553 us) -- REMOVE ALL BARRIERS.
// Blocks are exactly one wave (64 threads). DS ops from one wave execute in
// instruction order wave-wide: a ds_read issued after a ds_write sees the
// data, cross-lane included (mechanism already proven by sweep_invert, which
// has done barrier-free write->broadcast-read since R5 and passes).
// __syncthreads was compiling to s_waitcnt vmcnt(0) lgkmcnt(0) + s_barrier --
// a full memory drain ~480x per wave (3/iter x 160 ADMM iters), serializing
// all LDS AND global (incl. spill) traffic. Evidence this is the real cost:
// VALUBusy x dur is ~constant (380-470 us-equiv) across R2-R7 regardless of
// spills/LDS-op count, and the best run is the highest-occupancy one.

constexpr float SIG  = 1e-6f;
constexpr float C2   = 1.0f / (4.0f + 1e-6f);   // 1/(4+sigma): slack Schur diag
constexpr int   ITRS = 80;
constexpr int   LDA  = 68;                       // LDS stride for A (16B-aligned rows)

__device__ __forceinline__ float rl(float v, int lane) {
  return __uint_as_float(__builtin_amdgcn_readlane(__float_as_uint(v), lane));
}

// v_rcp_f32 + one Newton step: ~full fp32 precision reciprocal.
__device__ __forceinline__ float rcp_nr(float x) {
  float r = __builtin_amdgcn_rcpf(x);
  return r * fmaf(-x, r, 2.0f);
}

// Symmetric sweep-operator inversion. Lane t holds row t (== col t) of the
// symmetric working matrix W, rotated so the current pivot is local index 0.
// After 64 sweeps: Cm[j] = -Sinv[t][j]. Single-wave blocks; cross-lane data
// moves via lsrow with per-wave in-order DS (no barrier needed).
__device__ __forceinline__ void sweep_invert(float (&Cm)[64], float* lsrow, int t) {
#pragma unroll 1
  for (int p = 0; p < 64; ++p) {
    lsrow[(t - p) & 63] = Cm[0];         // W[t][p]: permutation write, conflict-free
    float alpha = lsrow[0];              // broadcast: W[p][p]
    float inva  = rcp_nr(alpha);
    bool  isP   = (t == p);
    float u0    = Cm[0] * inva;
    float u     = isP ? (1.0f - inva) : u0;   // per-lane sweep multiplier
    float last  = isP ? (-inva)       : u0;   // new column-p entry -> slot 63
#pragma unroll
    for (int j = 0; j < 16; ++j) {
      float4 rp = ((const float4*)lsrow)[j];  // broadcast pivot row chunk
      int m0 = 4 * j;
      if (j) Cm[m0 - 1] = fmaf(-u, rp.x, Cm[m0]);
      Cm[m0 + 0] = fmaf(-u, rp.y, Cm[m0 + 1]);
      Cm[m0 + 1] = fmaf(-u, rp.z, Cm[m0 + 2]);
      Cm[m0 + 2] = fmaf(-u, rp.w, Cm[m0 + 3]);
    }
    Cm[63] = last;
  }
}

__global__ __launch_bounds__(64, 4) void fw_kernel(
    const float* __restrict__ xraw, const float* __restrict__ A,
    const float* __restrict__ b, const float* __restrict__ W1,
    const float* __restrict__ W1T, const float* __restrict__ w2,
    float* __restrict__ out) {
  const int n = blockIdx.x, t = threadIdx.x;
  const float* Ap = A + (size_t)n * 2048;

  __shared__ __align__(16) float lsA[32 * LDA];   // 8704 B, raw A (never rewritten)
  __shared__ __align__(16) float sbuf[256];       // 1024 B, multi-purpose
  float* lst1 = sbuf;            // [64]  ADMM t1 broadcast / sweep lsrow
  float* lsx  = sbuf + 64;       // [64]  ADMM x broadcast
  float* lsv2 = sbuf + 128;      // [32]  ADMM v2 broadcast
  float* lsrn = sbuf + 176;      // [32]  1/rownorm (LMO phase)
  // MLP phase reuses sbuf[0..255] as the u-vector.
  // NOTE: no __syncthreads anywhere -- single-wave block, DS is in-order.

  // ---- stage A into LDS (float4 both sides) ----
  const float4* Apv = (const float4*)Ap;
#pragma unroll
  for (int jj = 0; jj < 8; ++jj) {
    float4 a4 = Apv[t + 64 * jj];
    int k = (t >> 4) + 4 * jj;        // row
    int col = 4 * (t & 15);
    *((float4*)&lsA[k * LDA + col]) = a4;
  }

  const int r = t & 31, c0 = (t >> 5) << 5;

  // ================= anchor QP: build S, invert =================
  // S column t: (2+sig)I + A^T A - C2 * As^T As  (As = rows 28..31)
  float Cm[64];
#pragma unroll
  for (int i = 0; i < 64; ++i) Cm[i] = 0.f;
#pragma unroll 1
  for (int k = 0; k < 32; ++k) {
    float wk = (k < 28) ? 1.0f : (1.0f - C2);
    float ak = wk * lsA[k * LDA + t];  // spread read (dynamic k: LDS, not regs)
#pragma unroll
    for (int ii = 0; ii < 16; ++ii) {
      float4 a4 = *((const float4*)&lsA[k * LDA + 4 * ii]);  // broadcast
      Cm[4 * ii + 0] = fmaf(ak, a4.x, Cm[4 * ii + 0]);
      Cm[4 * ii + 1] = fmaf(ak, a4.y, Cm[4 * ii + 1]);
      Cm[4 * ii + 2] = fmaf(ak, a4.z, Cm[4 * ii + 2]);
      Cm[4 * ii + 3] = fmaf(ak, a4.w, Cm[4 * ii + 3]);
    }
  }
#pragma unroll
  for (int i = 0; i < 64; ++i) Cm[i] += (i == t) ? (2.0f + SIG) : 0.0f;

  sweep_invert(Cm, lst1, t);   // Cm[j] = -Sinv[t][j]

  float acol[32];
#pragma unroll
  for (int k = 0; k < 32; ++k) acol[k] = lsA[k * LDA + t];   // A[k][t], static idx

  const float xf = xraw[(size_t)n * 64 + t];
  const float bl = (t < 32) ? b[(size_t)n * 32 + t] : 0.f;

  // ================= anchor ADMM =================
  float x_loc = 0.f, s_loc = 0.f;
  float z1 = 0.f, y1 = 0.f;                       // rows t: l=0,u=inf
  float z2 = (t < 32) ? fminf(0.f, bl) : 0.f;     // rows 64+r (lanes<32)
  float y2 = 0.f;
  float z3 = 0.f, y3 = 0.f;                       // lanes 28..31: slack bound rows

#pragma unroll 1
  for (int it = 0; it < ITRS; ++it) {
    float v2 = z2 - y2;                            // meaningful lanes<32
    if (t < 32) lsv2[t] = v2;
    float v3 = z3 - y3;                            // lanes 28..31, local

    // rhs x-part: sig*x + xf + v1 + A^T v2   (v2 via LDS broadcast, 4-way ILP)
    float r10 = fmaf(SIG, x_loc, xf) + (z1 - y1);
    float r11 = 0.f, r12 = 0.f, r13 = 0.f;
#pragma unroll
    for (int kk = 0; kk < 8; ++kk) {
      float4 v4 = ((const float4*)lsv2)[kk];       // broadcast
      r10 = fmaf(acol[4 * kk + 0], v4.x, r10);
      r11 = fmaf(acol[4 * kk + 1], v4.y, r11);
      r12 = fmaf(acol[4 * kk + 2], v4.z, r12);
      r13 = fmaf(acol[4 * kk + 3], v4.w, r13);
    }
    float r1 = (r10 + r11) + (r12 + r13);

    // rhs s-part (meaningful lanes 28..31): sig*s - v[92+i] + v[96+i]
    float r2v = fmaf(SIG, s_loc, v3 - v2);

    // t1 = r1 + C2 * As^T r2   (4 cross-lane scalars, constant lanes)
    float acc = 0.f;
    acc = fmaf(acol[28], rl(r2v, 28), acc);
    acc = fmaf(acol[29], rl(r2v, 29), acc);
    acc = fmaf(acol[30], rl(r2v, 30), acc);
    acc = fmaf(acol[31], rl(r2v, 31), acc);
    lst1[t] = fmaf(C2, acc, r1);

    // x = Sinv * t1 = -(W * t1): minus folds into FMA input modifier (free)
    float xn0 = 0.f, xn1 = 0.f, xn2 = 0.f, xn3 = 0.f;
#pragma unroll
    for (int jj = 0; jj < 16; ++jj) {
      float4 t4 = ((const float4*)lst1)[jj];       // broadcast
      xn0 = fmaf(-Cm[4 * jj + 0], t4.x, xn0);
      xn1 = fmaf(-Cm[4 * jj + 1], t4.y, xn1);
      xn2 = fmaf(-Cm[4 * jj + 2], t4.z, xn2);
      xn3 = fmaf(-Cm[4 * jj + 3], t4.w, xn3);
    }
    float xn = (xn0 + xn1) + (xn2 + xn3);
    x_loc = xn;
    lsx[t] = xn;

    // (A x)[r]: A row from LDS (spread b128), x via 2-addr broadcast reads
    float pa0 = 0.f, pa1 = 0.f, pa2 = 0.f, pa3 = 0.f;
#pragma unroll
    for (int jj = 0; jj < 8; ++jj) {
      float4 x4 = ((const float4*)(lsx + c0))[jj];
      float4 a4 = *((const float4*)&lsA[r * LDA + c0 + 4 * jj]);
      pa0 = fmaf(a4.x, x4.x, pa0);
      pa1 = fmaf(a4.y, x4.y, pa1);
      pa2 = fmaf(a4.z, x4.z, pa2);
      pa3 = fmaf(a4.w, x4.w, pa3);
    }
    float pa = (pa0 + pa1) + (pa2 + pa3);
    pa += __shfl_xor(pa, 32);

    // s = C2*(r2 + As x)  (meaningful lanes 28..31)
    float s_new = C2 * (r2v + pa);

    // z,y updates
    { float q1 = xn + y1; z1 = fmaxf(q1, 0.f); y1 = q1 - z1; }
    if (t < 32) {
      float Cx2 = pa - ((t >= 28) ? s_new : 0.f);  // rows 92..95: As x - s
      float q2 = Cx2 + y2; z2 = fminf(q2, bl); y2 = q2 - z2;
    }
    s_loc = s_new;
    { float q3 = s_new + y3; z3 = fmaxf(q3, 0.f); y3 = q3 - z3; }  // lanes 28..31
  }
  const float xfeas_r = x_loc;   // lsx still holds x_feas

  // ================= MLP gradient =================
  float4 hacc = make_float4(0.f, 0.f, 0.f, 0.f);
  const float4* W1v = (const float4*)W1;
#pragma unroll 2
  for (int j4 = 0; j4 < 16; ++j4) {
    float4 x4 = ((const float4*)lsx)[j4];          // broadcast
    float xj[4] = {x4.x, x4.y, x4.z, x4.w};
#pragma unroll
    for (int jj = 0; jj < 4; ++jj) {
      float4 w = W1v[(4 * j4 + jj) * 64 + t];
      hacc.x = fmaf(xj[jj], w.x, hacc.x);
      hacc.y = fmaf(xj[jj], w.y, hacc.y);
      hacc.z = fmaf(xj[jj], w.z, hacc.z);
      hacc.w = fmaf(xj[jj], w.w, hacc.w);
    }
  }
  float4 wv = ((const float4*)w2)[t];
  float hx, u0, u1, u2, u3;
  hx = tanhf(hacc.x); u0 = (1.f - hx * hx) * wv.x;
  hx = tanhf(hacc.y); u1 = (1.f - hx * hx) * wv.y;
  hx = tanhf(hacc.z); u2 = (1.f - hx * hx) * wv.z;
  hx = tanhf(hacc.w); u3 = (1.f - hx * hx) * wv.w;
  // all lsx/lst1 reads above precede this write in program order (in-order DS)
  ((float4*)sbuf)[t] = make_float4(u0, u1, u2, u3);   // sbuf = u[256]

  // g[t] = sum_c W1[t][c]*u[c]; W1T pre-packed: W1T4[c4*64+t] = W1[t][4c4..4c4+3]
  float g0 = 0.f, g1 = 0.f, g2 = 0.f, g3 = 0.f;
  const float4* L4 = (const float4*)W1T;
#pragma unroll 4
  for (int c4 = 0; c4 < 64; ++c4) {
    float4 u4 = ((const float4*)sbuf)[c4];   // broadcast
    float4 w4 = L4[c4 * 64 + t];             // coalesced
    g0 = fmaf(w4.x, u4.x, g0);
    g1 = fmaf(w4.y, u4.y, g1);
    g2 = fmaf(w4.z, u4.z, g2);
    g3 = fmaf(w4.w, u4.w, g3);
  }
  const float gl = (g0 + g1) + (g2 + g3);

  // ================= row norms (rows from LDS) =================
  float pr0 = 0.f, pr1 = 0.f, pr2 = 0.f, pr3 = 0.f;
#pragma unroll
  for (int jj = 0; jj < 8; ++jj) {
    float4 a4 = *((const float4*)&lsA[r * LDA + c0 + 4 * jj]);
    pr0 = fmaf(a4.x, a4.x, pr0);
    pr1 = fmaf(a4.y, a4.y, pr1);
    pr2 = fmaf(a4.z, a4.z, pr2);
    pr3 = fmaf(a4.w, a4.w, pr3);
  }
  float pr = (pr0 + pr1) + (pr2 + pr3);
  pr += __shfl_xor(pr, 32);
  if (t < 32) lsrn[t] = 1.0f / fmaxf(sqrtf(pr), 1e-12f);  // after u reads (in-order)

  const float rcp_r = lsrn[r];           // spread read, conflict-free
  const float bn = (t < 32) ? bl * rcp_r : 0.f;

  // normalized columns in regs (static indices; lsA stays raw)
#pragma unroll
  for (int k = 0; k < 32; ++k) acol[k] = lsA[k * LDA + t] * lsrn[k];

  // ================= LMO QP: build M, invert =================
  // M col t: (1+eps+sig)I + sum_k rcp_k^2 A[k][t] A[k][:]
#pragma unroll
  for (int i = 0; i < 64; ++i) Cm[i] = 0.f;
#pragma unroll 1
  for (int k = 0; k < 32; ++k) {
    float rn = lsrn[k];                  // broadcast (dynamic k: LDS)
    float ak = lsA[k * LDA + t] * rn * rn;
#pragma unroll
    for (int ii = 0; ii < 16; ++ii) {
      float4 a4 = *((const float4*)&lsA[k * LDA + 4 * ii]);  // raw row, broadcast
      Cm[4 * ii + 0] = fmaf(ak, a4.x, Cm[4 * ii + 0]);
      Cm[4 * ii + 1] = fmaf(ak, a4.y, Cm[4 * ii + 1]);
      Cm[4 * ii + 2] = fmaf(ak, a4.z, Cm[4 * ii + 2]);
      Cm[4 * ii + 3] = fmaf(ak, a4.w, Cm[4 * ii + 3]);
    }
  }
#pragma unroll
  for (int i = 0; i < 64; ++i) Cm[i] += (i == t) ? (1.0f + 1e-4f + SIG) : 0.0f;

  sweep_invert(Cm, lst1, t);   // Cm[j] = -Minv[t][j]

  // ================= LMO ADMM =================
  x_loc = 0.f; z1 = 0.f; y1 = 0.f;
  z2 = (t < 32) ? fminf(0.f, bn) : 0.f;
  y2 = 0.f;

#pragma unroll 1
  for (int it = 0; it < ITRS; ++it) {
    if (t < 32) lsv2[t] = z2 - y2;
    float r10 = fmaf(SIG, x_loc, gl) + (z1 - y1);
    float r11 = 0.f, r12 = 0.f, r13 = 0.f;
#pragma unroll
    for (int kk = 0; kk < 8; ++kk) {
      float4 v4 = ((const float4*)lsv2)[kk];       // broadcast
      r10 = fmaf(acol[4 * kk + 0], v4.x, r10);
      r11 = fmaf(acol[4 * kk + 1], v4.y, r11);
      r12 = fmaf(acol[4 * kk + 2], v4.z, r12);
      r13 = fmaf(acol[4 * kk + 3], v4.w, r13);
    }
    lst1[t] = (r10 + r11) + (r12 + r13);

    float xn0 = 0.f, xn1 = 0.f, xn2 = 0.f, xn3 = 0.f;
#pragma unroll
    for (int jj = 0; jj < 16; ++jj) {
      float4 t4 = ((const float4*)lst1)[jj];       // broadcast
      xn0 = fmaf(-Cm[4 * jj + 0], t4.x, xn0);
      xn1 = fmaf(-Cm[4 * jj + 1], t4.y, xn1);
      xn2 = fmaf(-Cm[4 * jj + 2], t4.z, xn2);
      xn3 = fmaf(-Cm[4 * jj + 3], t4.w, xn3);
    }
    float xn = (xn0 + xn1) + (xn2 + xn3);
    x_loc = xn;
    lsx[t] = xn;

    // (An x)[r] = rcp_r * (Araw[r] . x)
    float pa0 = 0.f, pa1 = 0.f, pa2 = 0.f, pa3 = 0.f;
#pragma unroll
    for (int jj = 0; jj < 8; ++jj) {
      float4 x4 = ((const float4*)(lsx + c0))[jj];
      float4 a4 = *((const float4*)&lsA[r * LDA + c0 + 4 * jj]);
      pa0 = fmaf(a4.x, x4.x, pa0);
      pa1 = fmaf(a4.y, x4.y, pa1);
      pa2 = fmaf(a4.z, x4.z, pa2);
      pa3 = fmaf(a4.w, x4.w, pa3);
    }
    float pa = (pa0 + pa1) + (pa2 + pa3);
    pa += __shfl_xor(pa, 32);
    pa *= rcp_r;

    { float q1 = xn + y1; z1 = fmaxf(q1, 0.f); y1 = q1 - z1; }
    if (t < 32) { float q2 = pa + y2; z2 = fminf(q2, bn); y2 = q2 - z2; }
  }

  out[(size_t)n * 64 + t] = fmaf(0.1f, x_loc, 0.9f * xfeas_r);
}

// ---- W1 re-pack: W1T[c4*256 + t*4 + j] = W1[t*256 + 4*c4 + j] (once) ----
__global__ void w1t_kernel(const float* __restrict__ W1, float* __restrict__ W1T) {
  int idx = blockIdx.x * 256 + threadIdx.x;
  if (idx < 64 * 256) {
    int c4 = idx >> 8, rem = idx & 255, tt = rem >> 2, j = rem & 3;
    W1T[idx] = W1[tt * 256 + 4 * c4 + j];
  }
}

extern "C" void kernel_launch(void* const* d_in, const int* in_sizes, int n_in,
                              void* d_out, int out_size, void* d_ws, size_t ws_size,
                              hipStream_t stream) {
  const float* xraw = (const float*)d_in[0];  // [N,64]
  const float* A    = (const float*)d_in[1];  // [N,32,64]
  const float* b    = (const float*)d_in[2];  // [N,32]
  const float* W1   = (const float*)d_in[3];  // [64,256]
  const float* w2   = (const float*)d_in[4];  // [256]
  float* out = (float*)d_out;

  const int nprob = in_sizes[0] / 64;
  float* W1T = (float*)d_ws;                  // 16384 floats

  w1t_kernel<<<64, 256, 0, stream>>>(W1, W1T);
  fw_kernel<<<nprob, 64, 0, stream>>>(xraw, A, b, W1, W1T, w2, out);
}

// Round 9
// 581.656 us; speedup vs baseline: 2.2600x; 2.2600x over previous
//
#include <hip/hip_runtime.h>
#include <math.h>

// FrankWolfePolicyImprovement, fused: 4096 problems; ONE WAVE RUNS TWO
// PROBLEMS side by side (2048 blocks x 64 threads). Phases per problem pair:
//   1. anchor QP  (Schur-reduced d=68 ADMM, 80 it, -Sinv rows in VGPRs)
//   2. tanh MLP gradient (W1/W1T global loads shared across the pair)
//   3. LMO QP on row-normalized A
//   4. blend + store
//
// Round-9 design (from R5-R8 evidence):
//  - The kernel is LATENCY-exposed: real VALU issue is ~190us of R5's 596us
//    wall (VALUBusy derived with gfx94x 4-cyc formula; CDNA4 is 2). Best run
//    so far (R6) won on occupancy DESPITE 2x spill inflation.
//  - Dual problems per wave doubles independent ILP in every chain segment
//    (two interleaved ADMM chains) at only 2 waves/SIMD residency, i.e. the
//    (64,2) 256-reg budget where the allocator is proven clean (R5).
//    Live ~230: Cm_a+Cm_b(128) + acol_a/b(64) + 2x state + narrow temps.
//  - Barriers KEPT: R8 (no barriers) caused a scheduler pressure explosion
//    (1.9 GB spill fetch). 3 __syncthreads/iter double as scheduling fences.
//  - sweep_invert (symmetric sweep operator) for both matrices per pivot:
//    in-order per-wave DS makes the write->broadcast-read safe (proven R5+).
//  - NO dynamic indexing into register arrays anywhere.

constexpr float SIG  = 1e-6f;
constexpr float C2   = 1.0f / (4.0f + 1e-6f);   // 1/(4+sigma): slack Schur diag
constexpr int   ITRS = 80;
constexpr int   LDA  = 68;                       // LDS stride for A (16B-aligned rows)

__device__ __forceinline__ float rl(float v, int lane) {
  return __uint_as_float(__builtin_amdgcn_readlane(__float_as_uint(v), lane));
}

// v_rcp_f32 + one Newton step: ~full fp32 precision reciprocal.
__device__ __forceinline__ float rcp_nr(float x) {
  float r = __builtin_amdgcn_rcpf(x);
  return r * fmaf(-x, r, 2.0f);
}

// Symmetric sweep-operator inversion of TWO matrices per pivot (ILP pair).
// Lane t holds row t (== col t) of each symmetric working matrix, rotated so
// the current pivot is local index 0. After 64 sweeps: C[j] = -Inv[t][j].
__device__ __forceinline__ void sweep_invert2(float (&Ca)[64], float (&Cb)[64],
                                              float* rowA, float* rowB, int t) {
#pragma unroll 1
  for (int p = 0; p < 64; ++p) {
    int idx = (t - p) & 63;
    rowA[idx] = Ca[0];                   // permutation writes, conflict-free
    rowB[idx] = Cb[0];
    float ivA = rcp_nr(rowA[0]);         // broadcast reads (in-order DS)
    float ivB = rcp_nr(rowB[0]);
    bool  isP = (t == p);
    float uA0 = Ca[0] * ivA,            uB0 = Cb[0] * ivB;
    float uA  = isP ? (1.0f - ivA) : uA0, uB = isP ? (1.0f - ivB) : uB0;
    float lA  = isP ? (-ivA)       : uA0, lB = isP ? (-ivB)       : uB0;
#pragma unroll
    for (int j = 0; j < 16; ++j) {
      float4 ra = ((const float4*)rowA)[j];
      float4 rb = ((const float4*)rowB)[j];
      int m0 = 4 * j;
      if (j) { Ca[m0 - 1] = fmaf(-uA, ra.x, Ca[m0]);
               Cb[m0 - 1] = fmaf(-uB, rb.x, Cb[m0]); }
      Ca[m0 + 0] = fmaf(-uA, ra.y, Ca[m0 + 1]);
      Cb[m0 + 0] = fmaf(-uB, rb.y, Cb[m0 + 1]);
      Ca[m0 + 1] = fmaf(-uA, ra.z, Ca[m0 + 2]);
      Cb[m0 + 1] = fmaf(-uB, rb.z, Cb[m0 + 2]);
      Ca[m0 + 2] = fmaf(-uA, ra.w, Ca[m0 + 3]);
      Cb[m0 + 2] = fmaf(-uB, rb.w, Cb[m0 + 3]);
    }
    Ca[63] = lA;
    Cb[63] = lB;
  }
}

__global__ __launch_bounds__(64, 2) void fw_kernel(
    const float* __restrict__ xraw, const float* __restrict__ A,
    const float* __restrict__ b, const float* __restrict__ W1,
    const float* __restrict__ W1T, const float* __restrict__ w2,
    float* __restrict__ out) {
  const int n0 = 2 * blockIdx.x, t = threadIdx.x;

  __shared__ __align__(16) float lsA0[32 * LDA];   // raw A, problem a
  __shared__ __align__(16) float lsA1[32 * LDA];   // raw A, problem b
  __shared__ __align__(16) float sb0[256];         // scratch, problem a
  __shared__ __align__(16) float sb1[256];         // scratch, problem b
  float* lst1a = sb0;       float* lst1b = sb1;        // [64] t1 bcast / sweep row
  float* lsxa  = sb0 + 64;  float* lsxb  = sb1 + 64;   // [64] x bcast
  float* lsv2a = sb0 + 128; float* lsv2b = sb1 + 128;  // [32] v2 bcast
  float* lsrna = sb0 + 176; float* lsrnb = sb1 + 176;  // [32] 1/rownorm
  // MLP phase reuses sb0/sb1 [0..255] as the two u-vectors.

  // ---- stage both A matrices into LDS (float4 both sides) ----
  const float4* Av0 = (const float4*)(A + (size_t)n0 * 2048);
  const float4* Av1 = (const float4*)(A + (size_t)(n0 + 1) * 2048);
#pragma unroll
  for (int jj = 0; jj < 8; ++jj) {
    float4 a0 = Av0[t + 64 * jj];
    float4 a1 = Av1[t + 64 * jj];
    int k = (t >> 4) + 4 * jj, col = 4 * (t & 15);
    *((float4*)&lsA0[k * LDA + col]) = a0;
    *((float4*)&lsA1[k * LDA + col]) = a1;
  }
  __syncthreads();

  const int r = t & 31, c0 = (t >> 5) << 5;

  // ================= anchor QP: build S (both), invert (both) =================
  float Ca[64], Cb[64];
#pragma unroll
  for (int i = 0; i < 64; ++i) { Ca[i] = 0.f; Cb[i] = 0.f; }
#pragma unroll 1
  for (int k = 0; k < 32; ++k) {
    float wk = (k < 28) ? 1.0f : (1.0f - C2);
    float aka = wk * lsA0[k * LDA + t];
    float akb = wk * lsA1[k * LDA + t];
#pragma unroll
    for (int ii = 0; ii < 16; ++ii) {
      float4 a0 = *((const float4*)&lsA0[k * LDA + 4 * ii]);  // broadcast
      float4 a1 = *((const float4*)&lsA1[k * LDA + 4 * ii]);
      Ca[4 * ii + 0] = fmaf(aka, a0.x, Ca[4 * ii + 0]);
      Cb[4 * ii + 0] = fmaf(akb, a1.x, Cb[4 * ii + 0]);
      Ca[4 * ii + 1] = fmaf(aka, a0.y, Ca[4 * ii + 1]);
      Cb[4 * ii + 1] = fmaf(akb, a1.y, Cb[4 * ii + 1]);
      Ca[4 * ii + 2] = fmaf(aka, a0.z, Ca[4 * ii + 2]);
      Cb[4 * ii + 2] = fmaf(akb, a1.z, Cb[4 * ii + 2]);
      Ca[4 * ii + 3] = fmaf(aka, a0.w, Ca[4 * ii + 3]);
      Cb[4 * ii + 3] = fmaf(akb, a1.w, Cb[4 * ii + 3]);
    }
  }
#pragma unroll
  for (int i = 0; i < 64; ++i) {
    float d = (i == t) ? (2.0f + SIG) : 0.0f;
    Ca[i] += d; Cb[i] += d;
  }

  sweep_invert2(Ca, Cb, lst1a, lst1b, t);   // C*[j] = -Sinv[t][j]

  float acol_a[32], acol_b[32];
#pragma unroll
  for (int k = 0; k < 32; ++k) {
    acol_a[k] = lsA0[k * LDA + t];
    acol_b[k] = lsA1[k * LDA + t];
  }

  const float xfa = xraw[(size_t)n0 * 64 + t];
  const float xfb = xraw[(size_t)(n0 + 1) * 64 + t];
  const float bla = (t < 32) ? b[(size_t)n0 * 32 + t] : 0.f;
  const float blb = (t < 32) ? b[(size_t)(n0 + 1) * 32 + t] : 0.f;

  // ================= anchor ADMM (both) =================
  float xa = 0.f, xb = 0.f, sa = 0.f, sbv = 0.f;
  float z1a = 0.f, y1a = 0.f, z1b = 0.f, y1b = 0.f;
  float z2a = (t < 32) ? fminf(0.f, bla) : 0.f, y2a = 0.f;
  float z2b = (t < 32) ? fminf(0.f, blb) : 0.f, y2b = 0.f;
  float z3a = 0.f, y3a = 0.f, z3b = 0.f, y3b = 0.f;   // lanes 28..31

#pragma unroll 1
  for (int it = 0; it < ITRS; ++it) {
    float v2a = z2a - y2a, v2b = z2b - y2b;
    if (t < 32) { lsv2a[t] = v2a; lsv2b[t] = v2b; }
    float v3a = z3a - y3a, v3b = z3b - y3b;
    __syncthreads();

    // rhs x-part both (2-wide accumulators; cross-problem ILP does the rest)
    float rA0 = fmaf(SIG, xa, xfa) + (z1a - y1a), rA1 = 0.f;
    float rB0 = fmaf(SIG, xb, xfb) + (z1b - y1b), rB1 = 0.f;
#pragma unroll
    for (int kk = 0; kk < 8; ++kk) {
      float4 va = ((const float4*)lsv2a)[kk];
      float4 vb = ((const float4*)lsv2b)[kk];
      rA0 = fmaf(acol_a[4 * kk + 0], va.x, rA0);
      rB0 = fmaf(acol_b[4 * kk + 0], vb.x, rB0);
      rA1 = fmaf(acol_a[4 * kk + 1], va.y, rA1);
      rB1 = fmaf(acol_b[4 * kk + 1], vb.y, rB1);
      rA0 = fmaf(acol_a[4 * kk + 2], va.z, rA0);
      rB0 = fmaf(acol_b[4 * kk + 2], vb.z, rB0);
      rA1 = fmaf(acol_a[4 * kk + 3], va.w, rA1);
      rB1 = fmaf(acol_b[4 * kk + 3], vb.w, rB1);
    }
    float r1a = rA0 + rA1, r1b = rB0 + rB1;

    float r2a = fmaf(SIG, sa, v3a - v2a);
    float r2b = fmaf(SIG, sbv, v3b - v2b);

    float accA = 0.f, accB = 0.f;
    accA = fmaf(acol_a[28], rl(r2a, 28), accA);
    accB = fmaf(acol_b[28], rl(r2b, 28), accB);
    accA = fmaf(acol_a[29], rl(r2a, 29), accA);
    accB = fmaf(acol_b[29], rl(r2b, 29), accB);
    accA = fmaf(acol_a[30], rl(r2a, 30), accA);
    accB = fmaf(acol_b[30], rl(r2b, 30), accB);
    accA = fmaf(acol_a[31], rl(r2a, 31), accA);
    accB = fmaf(acol_b[31], rl(r2b, 31), accB);
    lst1a[t] = fmaf(C2, accA, r1a);
    lst1b[t] = fmaf(C2, accB, r1b);
    __syncthreads();

    // x = Sinv*t1 = -(W*t1), both
    float xA0 = 0.f, xA1 = 0.f, xB0 = 0.f, xB1 = 0.f;
#pragma unroll
    for (int jj = 0; jj < 16; ++jj) {
      float4 ta = ((const float4*)lst1a)[jj];
      float4 tb = ((const float4*)lst1b)[jj];
      xA0 = fmaf(-Ca[4 * jj + 0], ta.x, xA0);
      xB0 = fmaf(-Cb[4 * jj + 0], tb.x, xB0);
      xA1 = fmaf(-Ca[4 * jj + 1], ta.y, xA1);
      xB1 = fmaf(-Cb[4 * jj + 1], tb.y, xB1);
      xA0 = fmaf(-Ca[4 * jj + 2], ta.z, xA0);
      xB0 = fmaf(-Cb[4 * jj + 2], tb.z, xB0);
      xA1 = fmaf(-Ca[4 * jj + 3], ta.w, xA1);
      xB1 = fmaf(-Cb[4 * jj + 3], tb.w, xB1);
    }
    float xna = xA0 + xA1, xnb = xB0 + xB1;
    xa = xna; xb = xnb;
    lsxa[t] = xna; lsxb[t] = xnb;
    __syncthreads();

    // (A x)[r] both: rows from LDS (spread b128), x via broadcast reads
    float pA0 = 0.f, pA1 = 0.f, pB0 = 0.f, pB1 = 0.f;
#pragma unroll
    for (int jj = 0; jj < 8; ++jj) {
      float4 x4a = ((const float4*)(lsxa + c0))[jj];
      float4 a4a = *((const float4*)&lsA0[r * LDA + c0 + 4 * jj]);
      float4 x4b = ((const float4*)(lsxb + c0))[jj];
      float4 a4b = *((const float4*)&lsA1[r * LDA + c0 + 4 * jj]);
      pA0 = fmaf(a4a.x, x4a.x, pA0);
      pB0 = fmaf(a4b.x, x4b.x, pB0);
      pA1 = fmaf(a4a.y, x4a.y, pA1);
      pB1 = fmaf(a4b.y, x4b.y, pB1);
      pA0 = fmaf(a4a.z, x4a.z, pA0);
      pB0 = fmaf(a4b.z, x4b.z, pB0);
      pA1 = fmaf(a4a.w, x4a.w, pA1);
      pB1 = fmaf(a4b.w, x4b.w, pB1);
    }
    float paA = pA0 + pA1; paA += __shfl_xor(paA, 32);
    float paB = pB0 + pB1; paB += __shfl_xor(paB, 32);

    float snA = C2 * (r2a + paA);
    float snB = C2 * (r2b + paB);

    { float q = xna + y1a; z1a = fmaxf(q, 0.f); y1a = q - z1a; }
    { float q = xnb + y1b; z1b = fmaxf(q, 0.f); y1b = q - z1b; }
    if (t < 32) {
      float CxA = paA - ((t >= 28) ? snA : 0.f);
      float qA = CxA + y2a; z2a = fminf(qA, bla); y2a = qA - z2a;
      float CxB = paB - ((t >= 28) ? snB : 0.f);
      float qB = CxB + y2b; z2b = fminf(qB, blb); y2b = qB - z2b;
    }
    sa = snA; sbv = snB;
    { float q = snA + y3a; z3a = fmaxf(q, 0.f); y3a = q - z3a; }
    { float q = snB + y3b; z3b = fmaxf(q, 0.f); y3b = q - z3b; }
  }
  const float xfeas_a = xa, xfeas_b = xb;   // lsxa/lsxb hold x_feas

  // ================= MLP gradient (both; W1 loads shared) =================
  float4 hA = make_float4(0.f, 0.f, 0.f, 0.f);
  float4 hB = make_float4(0.f, 0.f, 0.f, 0.f);
  const float4* W1v = (const float4*)W1;
#pragma unroll 2
  for (int j4 = 0; j4 < 16; ++j4) {
    float4 x4a = ((const float4*)lsxa)[j4];
    float4 x4b = ((const float4*)lsxb)[j4];
    float xja[4] = {x4a.x, x4a.y, x4a.z, x4a.w};
    float xjb[4] = {x4b.x, x4b.y, x4b.z, x4b.w};
#pragma unroll
    for (int jj = 0; jj < 4; ++jj) {
      float4 w = W1v[(4 * j4 + jj) * 64 + t];   // one load, two problems
      hA.x = fmaf(xja[jj], w.x, hA.x);  hB.x = fmaf(xjb[jj], w.x, hB.x);
      hA.y = fmaf(xja[jj], w.y, hA.y);  hB.y = fmaf(xjb[jj], w.y, hB.y);
      hA.z = fmaf(xja[jj], w.z, hA.z);  hB.z = fmaf(xjb[jj], w.z, hB.z);
      hA.w = fmaf(xja[jj], w.w, hA.w);  hB.w = fmaf(xjb[jj], w.w, hB.w);
    }
  }
  float4 wv = ((const float4*)w2)[t];
  float hx;
  float uA0, uA1, uA2, uA3, uB0, uB1, uB2, uB3;
  hx = tanhf(hA.x); uA0 = (1.f - hx * hx) * wv.x;
  hx = tanhf(hA.y); uA1 = (1.f - hx * hx) * wv.y;
  hx = tanhf(hA.z); uA2 = (1.f - hx * hx) * wv.z;
  hx = tanhf(hA.w); uA3 = (1.f - hx * hx) * wv.w;
  hx = tanhf(hB.x); uB0 = (1.f - hx * hx) * wv.x;
  hx = tanhf(hB.y); uB1 = (1.f - hx * hx) * wv.y;
  hx = tanhf(hB.z); uB2 = (1.f - hx * hx) * wv.z;
  hx = tanhf(hB.w); uB3 = (1.f - hx * hx) * wv.w;
  __syncthreads();                 // lsx/lst1 readers done before u overwrite
  ((float4*)sb0)[t] = make_float4(uA0, uA1, uA2, uA3);   // u_a
  ((float4*)sb1)[t] = make_float4(uB0, uB1, uB2, uB3);   // u_b
  __syncthreads();

  // g[t] both; W1T pre-packed: L4[c4*64+t] = W1[t][4c4..4c4+3], loaded once
  float gA0 = 0.f, gA1 = 0.f, gB0 = 0.f, gB1 = 0.f;
  const float4* L4 = (const float4*)W1T;
#pragma unroll 4
  for (int c4 = 0; c4 < 64; ++c4) {
    float4 ua = ((const float4*)sb0)[c4];    // broadcast
    float4 ub = ((const float4*)sb1)[c4];
    float4 w4 = L4[c4 * 64 + t];             // coalesced, shared
    gA0 = fmaf(w4.x, ua.x, gA0);  gB0 = fmaf(w4.x, ub.x, gB0);
    gA1 = fmaf(w4.y, ua.y, gA1);  gB1 = fmaf(w4.y, ub.y, gB1);
    gA0 = fmaf(w4.z, ua.z, gA0);  gB0 = fmaf(w4.z, ub.z, gB0);
    gA1 = fmaf(w4.w, ua.w, gA1);  gB1 = fmaf(w4.w, ub.w, gB1);
  }
  const float gla = gA0 + gA1, glb = gB0 + gB1;

  // ================= row norms (both) =================
  float nA0 = 0.f, nA1 = 0.f, nB0 = 0.f, nB1 = 0.f;
#pragma unroll
  for (int jj = 0; jj < 8; ++jj) {
    float4 a4a = *((const float4*)&lsA0[r * LDA + c0 + 4 * jj]);
    float4 a4b = *((const float4*)&lsA1[r * LDA + c0 + 4 * jj]);
    nA0 = fmaf(a4a.x, a4a.x, nA0);  nB0 = fmaf(a4b.x, a4b.x, nB0);
    nA1 = fmaf(a4a.y, a4a.y, nA1);  nB1 = fmaf(a4b.y, a4b.y, nB1);
    nA0 = fmaf(a4a.z, a4a.z, nA0);  nB0 = fmaf(a4b.z, a4b.z, nB0);
    nA1 = fmaf(a4a.w, a4a.w, nA1);  nB1 = fmaf(a4b.w, a4b.w, nB1);
  }
  float prA = nA0 + nA1; prA += __shfl_xor(prA, 32);
  float prB = nB0 + nB1; prB += __shfl_xor(prB, 32);
  __syncthreads();                 // u readers done before lsrn overwrites
  if (t < 32) {
    lsrna[t] = 1.0f / fmaxf(sqrtf(prA), 1e-12f);
    lsrnb[t] = 1.0f / fmaxf(sqrtf(prB), 1e-12f);
  }
  __syncthreads();

  const float rcpra = lsrna[r], rcprb = lsrnb[r];      // spread, 2-way (free)
  const float bna = (t < 32) ? bla * rcpra : 0.f;
  const float bnb = (t < 32) ? blb * rcprb : 0.f;

#pragma unroll
  for (int k = 0; k < 32; ++k) {
    acol_a[k] = lsA0[k * LDA + t] * lsrna[k];
    acol_b[k] = lsA1[k * LDA + t] * lsrnb[k];
  }

  // ================= LMO QP: build M (both), invert (both) =================
#pragma unroll
  for (int i = 0; i < 64; ++i) { Ca[i] = 0.f; Cb[i] = 0.f; }
#pragma unroll 1
  for (int k = 0; k < 32; ++k) {
    float rna = lsrna[k], rnb = lsrnb[k];
    float aka = lsA0[k * LDA + t] * rna * rna;
    float akb = lsA1[k * LDA + t] * rnb * rnb;
#pragma unroll
    for (int ii = 0; ii < 16; ++ii) {
      float4 a0 = *((const float4*)&lsA0[k * LDA + 4 * ii]);
      float4 a1 = *((const float4*)&lsA1[k * LDA + 4 * ii]);
      Ca[4 * ii + 0] = fmaf(aka, a0.x, Ca[4 * ii + 0]);
      Cb[4 * ii + 0] = fmaf(akb, a1.x, Cb[4 * ii + 0]);
      Ca[4 * ii + 1] = fmaf(aka, a0.y, Ca[4 * ii + 1]);
      Cb[4 * ii + 1] = fmaf(akb, a1.y, Cb[4 * ii + 1]);
      Ca[4 * ii + 2] = fmaf(aka, a0.z, Ca[4 * ii + 2]);
      Cb[4 * ii + 2] = fmaf(akb, a1.z, Cb[4 * ii + 2]);
      Ca[4 * ii + 3] = fmaf(aka, a0.w, Ca[4 * ii + 3]);
      Cb[4 * ii + 3] = fmaf(akb, a1.w, Cb[4 * ii + 3]);
    }
  }
#pragma unroll
  for (int i = 0; i < 64; ++i) {
    float d = (i == t) ? (1.0f + 1e-4f + SIG) : 0.0f;
    Ca[i] += d; Cb[i] += d;
  }

  sweep_invert2(Ca, Cb, lst1a, lst1b, t);   // C*[j] = -Minv[t][j]

  // ================= LMO ADMM (both) =================
  xa = 0.f; xb = 0.f;
  z1a = 0.f; y1a = 0.f; z1b = 0.f; y1b = 0.f;
  z2a = (t < 32) ? fminf(0.f, bna) : 0.f; y2a = 0.f;
  z2b = (t < 32) ? fminf(0.f, bnb) : 0.f; y2b = 0.f;

#pragma unroll 1
  for (int it = 0; it < ITRS; ++it) {
    if (t < 32) { lsv2a[t] = z2a - y2a; lsv2b[t] = z2b - y2b; }
    __syncthreads();
    float rA0 = fmaf(SIG, xa, gla) + (z1a - y1a), rA1 = 0.f;
    float rB0 = fmaf(SIG, xb, glb) + (z1b - y1b), rB1 = 0.f;
#pragma unroll
    for (int kk = 0; kk < 8; ++kk) {
      float4 va = ((const float4*)lsv2a)[kk];
      float4 vb = ((const float4*)lsv2b)[kk];
      rA0 = fmaf(acol_a[4 * kk + 0], va.x, rA0);
      rB0 = fmaf(acol_b[4 * kk + 0], vb.x, rB0);
      rA1 = fmaf(acol_a[4 * kk + 1], va.y, rA1);
      rB1 = fmaf(acol_b[4 * kk + 1], vb.y, rB1);
      rA0 = fmaf(acol_a[4 * kk + 2], va.z, rA0);
      rB0 = fmaf(acol_b[4 * kk + 2], vb.z, rB0);
      rA1 = fmaf(acol_a[4 * kk + 3], va.w, rA1);
      rB1 = fmaf(acol_b[4 * kk + 3], vb.w, rB1);
    }
    lst1a[t] = rA0 + rA1;
    lst1b[t] = rB0 + rB1;
    __syncthreads();

    float xA0 = 0.f, xA1 = 0.f, xB0 = 0.f, xB1 = 0.f;
#pragma unroll
    for (int jj = 0; jj < 16; ++jj) {
      float4 ta = ((const float4*)lst1a)[jj];
      float4 tb = ((const float4*)lst1b)[jj];
      xA0 = fmaf(-Ca[4 * jj + 0], ta.x, xA0);
      xB0 = fmaf(-Cb[4 * jj + 0], tb.x, xB0);
      xA1 = fmaf(-Ca[4 * jj + 1], ta.y, xA1);
      xB1 = fmaf(-Cb[4 * jj + 1], tb.y, xB1);
      xA0 = fmaf(-Ca[4 * jj + 2], ta.z, xA0);
      xB0 = fmaf(-Cb[4 * jj + 2], tb.z, xB0);
      xA1 = fmaf(-Ca[4 * jj + 3], ta.w, xA1);
      xB1 = fmaf(-Cb[4 * jj + 3], tb.w, xB1);
    }
    float xna = xA0 + xA1, xnb = xB0 + xB1;
    xa = xna; xb = xnb;
    lsxa[t] = xna; lsxb[t] = xnb;
    __syncthreads();

    float pA0 = 0.f, pA1 = 0.f, pB0 = 0.f, pB1 = 0.f;
#pragma unroll
    for (int jj = 0; jj < 8; ++jj) {
      float4 x4a = ((const float4*)(lsxa + c0))[jj];
      float4 a4a = *((const float4*)&lsA0[r * LDA + c0 + 4 * jj]);
      float4 x4b = ((const float4*)(lsxb + c0))[jj];
      float4 a4b = *((const float4*)&lsA1[r * LDA + c0 + 4 * jj]);
      pA0 = fmaf(a4a.x, x4a.x, pA0);
      pB0 = fmaf(a4b.x, x4b.x, pB0);
      pA1 = fmaf(a4a.y, x4a.y, pA1);
      pB1 = fmaf(a4b.y, x4b.y, pB1);
      pA0 = fmaf(a4a.z, x4a.z, pA0);
      pB0 = fmaf(a4b.z, x4b.z, pB0);
      pA1 = fmaf(a4a.w, x4a.w, pA1);
      pB1 = fmaf(a4b.w, x4b.w, pB1);
    }
    float paA = pA0 + pA1; paA += __shfl_xor(paA, 32); paA *= rcpra;
    float paB = pB0 + pB1; paB += __shfl_xor(paB, 32); paB *= rcprb;

    { float q = xna + y1a; z1a = fmaxf(q, 0.f); y1a = q - z1a; }
    { float q = xnb + y1b; z1b = fmaxf(q, 0.f); y1b = q - z1b; }
    if (t < 32) {
      float qA = paA + y2a; z2a = fminf(qA, bna); y2a = qA - z2a;
      float qB = paB + y2b; z2b = fminf(qB, bnb); y2b = qB - z2b;
    }
  }

  out[(size_t)n0 * 64 + t]       = fmaf(0.1f, xa, 0.9f * xfeas_a);
  out[(size_t)(n0 + 1) * 64 + t] = fmaf(0.1f, xb, 0.9f * xfeas_b);
}

// ---- W1 re-pack: W1T[c4*256 + t*4 + j] = W1[t*256 + 4*c4 + j] (once) ----
__global__ void w1t_kernel(const float* __restrict__ W1, float* __restrict__ W1T) {
  int idx = blockIdx.x * 256 + threadIdx.x;
  if (idx < 64 * 256) {
    int c4 = idx >> 8, rem = idx & 255, tt = rem >> 2, j = rem & 3;
    W1T[idx] = W1[tt * 256 + 4 * c4 + j];
  }
}

extern "C" void kernel_launch(void* const* d_in, const int* in_sizes, int n_in,
                              void* d_out, int out_size, void* d_ws, size_t ws_size,
                              hipStream_t stream) {
  const float* xraw = (const float*)d_in[0];  // [N,64]
  const float* A    = (const float*)d_in[1];  // [N,32,64]
  const float* b    = (const float*)d_in[2];  // [N,32]
  const float* W1   = (const float*)d_in[3];  // [64,256]
  const float* w2   = (const float*)d_in[4];  // [256]
  float* out = (float*)d_out;

  const int nprob = in_sizes[0] / 64;
  float* W1T = (float*)d_ws;                  // 16384 floats

  w1t_kernel<<<64, 256, 0, stream>>>(W1, W1T);
  fw_kernel<<<nprob / 2, 64, 0, stream>>>(xraw, A, b, W1, W1T, w2, out);
}